// Round 9
// baseline (927.731 us; speedup 1.0000x reference)
//
#include <hip/hip_runtime.h>
#include <hip/hip_bf16.h>

#define TT 128
#define BB 128
#define HH 1024
#define PP 32
#define G7 7168

typedef __attribute__((ext_vector_type(8))) short short8;
typedef __attribute__((ext_vector_type(4))) float f32x4;

__device__ __forceinline__ ushort f2bf(float f) {
    union { float f; unsigned int u; } v; v.f = f;
    unsigned int u = v.u;
    return (ushort)((u + 0x7FFFu + ((u >> 16) & 1u)) >> 16);
}
__device__ __forceinline__ float sigm(float x) { return 1.f / (1.f + __expf(-x)); }
__device__ __forceinline__ float ftanh(float x) {
    float e = __expf(2.f * x);
    return 1.f - 2.f / (e + 1.f);
}

// ---- prep: repack W rows 32..1055 into MFMA-fragment-major bf16 layout ----
// W2[(nt*32 + ki)*64 + lane][e] = W[32 + ki*32 + (lane>>4)*8 + e][nt*16 + (lane&15)]
__global__ void prep_w2(const float* __restrict__ W, ushort* __restrict__ W2) {
    int nt = blockIdx.x;          // 0..447 (16-col n-tile)
    int ki = blockIdx.y;          // 0..31
    int lane = threadIdx.x;
    int n = nt * 16 + (lane & 15);
    int k = ki * 32 + (lane >> 4) * 8;
    size_t off = ((size_t)(nt * 32 + ki) * 64 + lane) * 8;
    #pragma unroll
    for (int e = 0; e < 8; ++e)
        W2[off + e] = f2bf(W[(size_t)(32 + k + e) * G7 + n]);
}

// ---- prep: G0[type][n] = b[n] + embed[type] @ W[0:32] ----
__global__ void prep_g0(const float* __restrict__ W, const float* __restrict__ embed,
                        const float* __restrict__ bias, float* __restrict__ G0) {
    int n = blockIdx.x * 256 + threadIdx.x;
    int ty = blockIdx.y;
    float acc = bias[n];
    for (int p = 0; p < PP; ++p)
        acc += embed[ty * PP + p] * W[(size_t)p * G7 + n];
    G0[(size_t)ty * G7 + n] = acc;
}

// ---- prep: A4 layout from h0; state init ----
// A4 index: (((bq*32 + ki)*2 + bfr)*64 + lane)*8 + e
__global__ void prep_init(const float* __restrict__ h0, const float* __restrict__ c0,
                          ushort* __restrict__ A4, float* __restrict__ c_state) {
    int i = blockIdx.x * 256 + threadIdx.x;
    int b = i >> 10, k = i & 1023;
    int lane = (b & 15) | (((k >> 3) & 3) << 4);
    size_t off = ((size_t)(((b >> 5) * 32 + (k >> 5)) * 2 + ((b >> 4) & 1)) * 64 + lane) * 8 + (k & 7);
    A4[off] = f2bf(h0[i]);
    c_state[i] = c0[i];
}

// ---- per-step fused kernel ----
// grid 256 = 64 h-tiles x 4 b-quarters; block 896 thr = 14 waves = 7 gates x 2 K-sets.
// Wave (g,kh) covers interleaved ki = {c*8 + kh + 2j}; M=32 per wave.
// A staged in 4 pipelined 16KB chunks; W double-buffered in registers.
__global__ __launch_bounds__(896) void step_kernel(
    const ushort* __restrict__ W2, const float* __restrict__ G0,
    const float* __restrict__ dts, const int* __restrict__ types,
    const float* __restrict__ c0,
    const ushort* __restrict__ a_read, ushort* __restrict__ a_write,
    float* __restrict__ c_state, float* __restrict__ out, int t)
{
    __shared__ short8 Albuf[4096];     // 64 KB: [ki 0..31][bfr 0..1][lane]
    __shared__ f32x4 pbuf[7][2][64];   // 14 KB: K-set partials
    __shared__ float gbuf[7][32][17];  // padded: no 4-way bank conflicts
    const int tid = threadIdx.x;
    const int wave = tid >> 6, lane = tid & 63;
    const int g = wave >> 1, kh = wave & 1;
    const int bid = blockIdx.x;
    // XCD-pin: bid&7 = XCD; XCD x owns h-cols [x*128,(x+1)*128)
    const int ht = (bid & 7) * 8 + ((bid >> 3) & 7);  // 0..63
    const int bq = bid >> 6;                          // 0..3 (32-row b-quarter)

    const short8* Asrc = reinterpret_cast<const short8*>(a_read) + bq * 4096;
    const short8* Wv = reinterpret_cast<const short8*>(W2)
                     + (size_t)(g * 64 + ht) * 2048 + lane;

    // ---- stage chunk 0 (16 KB) + preload its W frags ----
    Albuf[tid] = Asrc[tid];
    if (tid < 128) Albuf[896 + tid] = Asrc[896 + tid];
    short8 wr0[4], wr1[4];
    #pragma unroll
    for (int j = 0; j < 4; ++j)
        wr0[j] = Wv[(kh + 2 * j) * 64];
    __syncthreads();

    // ---- pipelined K-loop: compute chunk c while staging chunk c+1 ----
    f32x4 acc0 = {}, acc1 = {};
    #pragma unroll
    for (int c = 0; c < 4; ++c) {
        if (c < 3) {
            Albuf[(c + 1) * 1024 + tid] = Asrc[(c + 1) * 1024 + tid];
            if (tid < 128)
                Albuf[(c + 1) * 1024 + 896 + tid] = Asrc[(c + 1) * 1024 + 896 + tid];
            #pragma unroll
            for (int j = 0; j < 4; ++j)
                wr1[j] = Wv[((c + 1) * 8 + kh + 2 * j) * 64];
        }
        const short8* As = Albuf + c * 1024 + lane;
        #pragma unroll
        for (int j = 0; j < 4; ++j) {
            const int kloc = kh + 2 * j;
            short8 a0 = As[(kloc * 2 + 0) * 64];
            short8 a1 = As[(kloc * 2 + 1) * 64];
            acc0 = __builtin_amdgcn_mfma_f32_16x16x32_bf16(a0, wr0[j], acc0, 0, 0, 0);
            acc1 = __builtin_amdgcn_mfma_f32_16x16x32_bf16(a1, wr0[j], acc1, 0, 0, 0);
        }
        __syncthreads();
        #pragma unroll
        for (int j = 0; j < 4; ++j) wr0[j] = wr1[j];
    }

    // ---- cross-wave K-reduce ----
    if (kh == 1) { pbuf[g][0][lane] = acc0; pbuf[g][1][lane] = acc1; }
    __syncthreads();
    if (kh == 0) {
        acc0 += pbuf[g][0][lane];
        acc1 += pbuf[g][1][lane];
        // C/D layout (verified): b-row = (lane>>4)*4 + r, h-col = lane&15
        const int rb = (lane >> 4) * 4, lr = lane & 15;
        #pragma unroll
        for (int r = 0; r < 4; ++r) {
            gbuf[g][rb + r][lr]      = acc0[r];
            gbuf[g][16 + rb + r][lr] = acc1[r];
        }
    }
    __syncthreads();

    // ---- epilogue: 512 elements (32 b-rows x 16 h-cols) ----
    if (tid < 512) {
        const int br = tid >> 4, hc = tid & 15;
        const int b = bq * 32 + br;
        const int h = ht * 16 + hc;
        const int ty = types[t * BB + b];
        const float dt = dts[t * BB + b];
        const float* g0p = G0 + (size_t)ty * G7 + h;
        float pre[7];
        #pragma unroll
        for (int gg = 0; gg < 7; ++gg)
            pre[gg] = gbuf[gg][br][hc] + g0p[gg * HH];

        float inpt   = sigm(pre[0]);
        float forget = sigm(pre[1]);
        float output = sigm(pre[2]);
        float itg    = sigm(pre[3]);
        float ftg    = sigm(pre[4]);
        float z      = ftanh(pre[5]);
        float x8     = 8.f * pre[6];
        float sp     = fmaxf(x8, 0.f) + __logf(1.f + __expf(-fabsf(x8)));
        float decay  = sp * 0.125f;

        const size_t si = (size_t)b * HH + h;
        const size_t OS = (size_t)TT * BB * HH;
        float c    = c_state[si];
        // previous ctgt comes from out[4] written by THIS block at t-1 (L2-hot)
        float ctgt = (t == 0) ? c0[si] : out[4 * OS + (size_t)(t - 1) * BB * HH + si];
        float c_i      = forget * c + inpt * z;
        float h_i      = output * ftanh(c_i);
        float ctgt_new = ftg * ctgt + itg * z;
        float edt      = __expf(-decay * dt);
        float c_new    = ctgt_new + (c_i - ctgt_new) * edt;
        float h_new    = output * ftanh(c_new);

        size_t ob = (size_t)t * BB * HH + si;
        __builtin_nontemporal_store(h_i,      &out[ob]);
        __builtin_nontemporal_store(h_new,    &out[OS + ob]);
        __builtin_nontemporal_store(output,   &out[2 * OS + ob]);
        __builtin_nontemporal_store(c_i,      &out[3 * OS + ob]);
        out[4 * OS + ob] = ctgt_new;   // cached: re-read next step
        __builtin_nontemporal_store(decay,    &out[5 * OS + ob]);
        c_state[si] = c_new;
        // h_new -> next step's A4 layout
        int ki_w = h >> 5;
        int lane_w = (b & 15) | (((h >> 3) & 3) << 4);
        size_t aoff = ((size_t)((((b >> 5) * 32 + ki_w) * 2 + ((b >> 4) & 1)) * 64) + lane_w) * 8 + (h & 7);
        a_write[aoff] = f2bf(h_new);
    }
}

extern "C" void kernel_launch(void* const* d_in, const int* in_sizes, int n_in,
                              void* d_out, int out_size, void* d_ws, size_t ws_size,
                              hipStream_t stream) {
    const float* seq_dt    = (const float*)d_in[0];
    const int*   seq_types = (const int*)d_in[1];
    const float* h0        = (const float*)d_in[2];
    const float* c0        = (const float*)d_in[3];
    const float* embed     = (const float*)d_in[4];
    const float* W         = (const float*)d_in[5];
    const float* bias      = (const float*)d_in[6];
    float* out = (float*)d_out;

    char* ws = (char*)d_ws;
    ushort* W2  = (ushort*)ws;                  // 14,680,064
    float*  G0b = (float*)(ws + 14680064);      //    946,176
    ushort* a40 = (ushort*)(ws + 15626240);     //    262,144
    ushort* a41 = (ushort*)(ws + 15888384);     //    262,144
    float*  cs  = (float*)(ws + 16150528);      //    524,288

    hipLaunchKernelGGL(prep_w2, dim3(448, 32), dim3(64), 0, stream, W, W2);
    hipLaunchKernelGGL(prep_g0, dim3(28, 33), dim3(256), 0, stream, W, embed, bias, G0b);
    hipLaunchKernelGGL(prep_init, dim3(512), dim3(256), 0, stream, h0, c0, a40, cs);

    for (int t = 0; t < TT; ++t) {
        const ushort* ar = (t & 1) ? a41 : a40;
        ushort*       aw = (t & 1) ? a40 : a41;
        hipLaunchKernelGGL(step_kernel, dim3(256), dim3(896), 0, stream,
                           W2, G0b, seq_dt, seq_types, c0, ar, aw, cs, out, t);
    }
}

// Round 10
// 829.373 us; speedup vs baseline: 1.1186x; 1.1186x over previous
//
#include <hip/hip_runtime.h>
#include <hip/hip_bf16.h>

#define TT 128
#define BB 128
#define HH 1024
#define PP 32
#define G7 7168

typedef __attribute__((ext_vector_type(8))) short short8;
typedef __attribute__((ext_vector_type(4))) float f32x4;

__device__ __forceinline__ ushort f2bf(float f) {
    union { float f; unsigned int u; } v; v.f = f;
    unsigned int u = v.u;
    return (ushort)((u + 0x7FFFu + ((u >> 16) & 1u)) >> 16);
}
__device__ __forceinline__ float sigm(float x) { return 1.f / (1.f + __expf(-x)); }
__device__ __forceinline__ float ftanh(float x) {
    float e = __expf(2.f * x);
    return 1.f - 2.f / (e + 1.f);
}

// ---- prep: repack W rows 32..1055 into MFMA-fragment-major bf16 layout ----
// W2[(nt*32 + ki)*64 + lane][e] = W[32 + ki*32 + (lane>>4)*8 + e][nt*16 + (lane&15)]
__global__ void prep_w2(const float* __restrict__ W, ushort* __restrict__ W2) {
    int nt = blockIdx.x;          // 0..447 (16-col n-tile)
    int ki = blockIdx.y;          // 0..31
    int lane = threadIdx.x;
    int n = nt * 16 + (lane & 15);
    int k = ki * 32 + (lane >> 4) * 8;
    size_t off = ((size_t)(nt * 32 + ki) * 64 + lane) * 8;
    #pragma unroll
    for (int e = 0; e < 8; ++e)
        W2[off + e] = f2bf(W[(size_t)(32 + k + e) * G7 + n]);
}

// ---- prep: G0[type][n] = b[n] + embed[type] @ W[0:32] ----
__global__ void prep_g0(const float* __restrict__ W, const float* __restrict__ embed,
                        const float* __restrict__ bias, float* __restrict__ G0) {
    int n = blockIdx.x * 256 + threadIdx.x;
    int ty = blockIdx.y;
    float acc = bias[n];
    for (int p = 0; p < PP; ++p)
        acc += embed[ty * PP + p] * W[(size_t)p * G7 + n];
    G0[(size_t)ty * G7 + n] = acc;
}

// ---- prep: A4 layout from h0; state init ----
// A4 index: (((bq*32 + ki)*2 + bfr)*64 + lane)*8 + e
__global__ void prep_init(const float* __restrict__ h0, const float* __restrict__ c0,
                          ushort* __restrict__ A4, float* __restrict__ c_state,
                          float* __restrict__ ctgt_state) {
    int i = blockIdx.x * 256 + threadIdx.x;
    int b = i >> 10, k = i & 1023;
    int lane = (b & 15) | (((k >> 3) & 3) << 4);
    size_t off = ((size_t)(((b >> 5) * 32 + (k >> 5)) * 2 + ((b >> 4) & 1)) * 64 + lane) * 8 + (k & 7);
    A4[off] = f2bf(h0[i]);
    c_state[i] = c0[i];
    ctgt_state[i] = c0[i];
}

// ---- per-step fused kernel (R8 structure, overhead trimmed) ----
// grid 256 = 64 h-tiles x 4 b-quarters; block 896 thr = 14 waves = 7 gates x 2 K-halves.
// M=32 per wave (2 acc chains share each W fragment) -> every W frag through L1 ONCE/CU.
// Both kh-waves write partials straight to gbuf; epilogue sums (no reduce barrier).
__global__ __launch_bounds__(896) void step_kernel(
    const ushort* __restrict__ W2, const float* __restrict__ G0,
    const float* __restrict__ dts, const int* __restrict__ types,
    const ushort* __restrict__ a_read, ushort* __restrict__ a_write,
    float* __restrict__ c_state, float* __restrict__ ctgt_state,
    float* __restrict__ out, int t)
{
    __shared__ short8 Albuf[4096];         // 64 KB: [ki 0..31][bfr 0..1][lane]
    __shared__ float gbuf[7][2][32][17];   // 30.5 KB padded: partials per K-half
    const int tid = threadIdx.x;
    const int wave = tid >> 6, lane = tid & 63;
    const int g = wave >> 1, kh = wave & 1;
    const int bid = blockIdx.x;
    // XCD-pin: bid&7 = XCD; XCD x owns h-cols [x*128,(x+1)*128)
    const int ht = (bid & 7) * 8 + ((bid >> 3) & 7);  // 0..63
    const int bq = bid >> 6;                          // 0..3 (32-row b-quarter)

    // ---- stage this b-quarter's A slice (64 KB, linear copy) ----
    const short8* Asrc = reinterpret_cast<const short8*>(a_read) + bq * 4096;
    #pragma unroll
    for (int r = 0; r < 4; ++r)
        Albuf[r * 896 + tid] = Asrc[r * 896 + tid];
    if (tid < 512) Albuf[3584 + tid] = Asrc[3584 + tid];
    __syncthreads();

    // ---- K-loop: wave (g,kh) covers K-half kh, M=32 (both b-frags) ----
    const short8* Wv = reinterpret_cast<const short8*>(W2)
                     + (size_t)(g * 64 + ht) * 2048 + (kh * 16) * 64 + lane;
    const short8* As = Albuf + (kh * 16) * 2 * 64 + lane;
    f32x4 acc0 = {}, acc1 = {};
    #pragma unroll 8
    for (int j = 0; j < 16; ++j) {
        short8 wf = Wv[j * 64];
        short8 a0 = As[(j * 2 + 0) * 64];
        short8 a1 = As[(j * 2 + 1) * 64];
        acc0 = __builtin_amdgcn_mfma_f32_16x16x32_bf16(a0, wf, acc0, 0, 0, 0);
        acc1 = __builtin_amdgcn_mfma_f32_16x16x32_bf16(a1, wf, acc1, 0, 0, 0);
    }

    // ---- both K-halves write partials to gbuf (no cross-wave reduce pass) ----
    // C/D layout (verified): b-row = (lane>>4)*4 + r, h-col = lane&15
    {
        const int rb = (lane >> 4) * 4, lr = lane & 15;
        #pragma unroll
        for (int r = 0; r < 4; ++r) {
            gbuf[g][kh][rb + r][lr]      = acc0[r];
            gbuf[g][kh][16 + rb + r][lr] = acc1[r];
        }
    }
    __syncthreads();

    // ---- epilogue: 512 elements (32 b-rows x 16 h-cols) ----
    if (tid < 512) {
        const int br = tid >> 4, hc = tid & 15;
        const int b = bq * 32 + br;
        const int h = ht * 16 + hc;
        const int ty = types[t * BB + b];
        const float dt = dts[t * BB + b];
        const float* g0p = G0 + (size_t)ty * G7 + h;
        float pre[7];
        #pragma unroll
        for (int gg = 0; gg < 7; ++gg)
            pre[gg] = gbuf[gg][0][br][hc] + gbuf[gg][1][br][hc] + g0p[gg * HH];

        float inpt   = sigm(pre[0]);
        float forget = sigm(pre[1]);
        float output = sigm(pre[2]);
        float itg    = sigm(pre[3]);
        float ftg    = sigm(pre[4]);
        float z      = ftanh(pre[5]);
        float x8     = 8.f * pre[6];
        float sp     = fmaxf(x8, 0.f) + __logf(1.f + __expf(-fabsf(x8)));
        float decay  = sp * 0.125f;

        const size_t si = (size_t)b * HH + h;
        float c    = c_state[si];
        float ctgt = ctgt_state[si];
        float c_i      = forget * c + inpt * z;
        float h_i      = output * ftanh(c_i);
        float ctgt_new = ftg * ctgt + itg * z;
        float edt      = __expf(-decay * dt);
        float c_new    = ctgt_new + (c_i - ctgt_new) * edt;
        float h_new    = output * ftanh(c_new);

        const size_t OS = (size_t)TT * BB * HH;
        size_t ob = (size_t)t * BB * HH + si;
        __builtin_nontemporal_store(h_i,      &out[ob]);
        __builtin_nontemporal_store(h_new,    &out[OS + ob]);
        __builtin_nontemporal_store(output,   &out[2 * OS + ob]);
        __builtin_nontemporal_store(c_i,      &out[3 * OS + ob]);
        __builtin_nontemporal_store(ctgt_new, &out[4 * OS + ob]);
        __builtin_nontemporal_store(decay,    &out[5 * OS + ob]);
        c_state[si]    = c_new;
        ctgt_state[si] = ctgt_new;

        // h_new -> next step's A4 layout; pack even/odd h into one dword store
        unsigned hb = (unsigned)f2bf(h_new);
        unsigned other = __shfl_down(hb, 1);
        if ((hc & 1) == 0) {
            int ki_w = h >> 5;
            int lane_w = (b & 15) | (((h >> 3) & 3) << 4);
            size_t aoff = ((size_t)((((b >> 5) * 32 + ki_w) * 2 + ((b >> 4) & 1)) * 64) + lane_w) * 8 + (h & 7);
            *reinterpret_cast<unsigned*>(a_write + aoff) = hb | (other << 16);
        }
    }
}

extern "C" void kernel_launch(void* const* d_in, const int* in_sizes, int n_in,
                              void* d_out, int out_size, void* d_ws, size_t ws_size,
                              hipStream_t stream) {
    const float* seq_dt    = (const float*)d_in[0];
    const int*   seq_types = (const int*)d_in[1];
    const float* h0        = (const float*)d_in[2];
    const float* c0        = (const float*)d_in[3];
    const float* embed     = (const float*)d_in[4];
    const float* W         = (const float*)d_in[5];
    const float* bias      = (const float*)d_in[6];
    float* out = (float*)d_out;

    char* ws = (char*)d_ws;
    ushort* W2  = (ushort*)ws;                  // 14,680,064
    float*  G0b = (float*)(ws + 14680064);      //    946,176
    ushort* a40 = (ushort*)(ws + 15626240);     //    262,144
    ushort* a41 = (ushort*)(ws + 15888384);     //    262,144
    float*  cs  = (float*)(ws + 16150528);      //    524,288
    float*  cts = (float*)(ws + 16674816);      //    524,288

    hipLaunchKernelGGL(prep_w2, dim3(448, 32), dim3(64), 0, stream, W, W2);
    hipLaunchKernelGGL(prep_g0, dim3(28, 33), dim3(256), 0, stream, W, embed, bias, G0b);
    hipLaunchKernelGGL(prep_init, dim3(512), dim3(256), 0, stream, h0, c0, a40, cs, cts);

    for (int t = 0; t < TT; ++t) {
        const ushort* ar = (t & 1) ? a41 : a40;
        ushort*       aw = (t & 1) ? a40 : a41;
        hipLaunchKernelGGL(step_kernel, dim3(256), dim3(896), 0, stream,
                           W2, G0b, seq_dt, seq_types, ar, aw, cs, cts, out, t);
    }
}